// Round 17
// baseline (1793.671 us; speedup 1.0000x reference)
//
#include <hip/hip_runtime.h>

// DynamicDeepSNN r17 — r16 with RB=1/TC=16: grid 512->1024 blocks so the
// 4-blocks/CU occupancy headroom (r16: LDS 39.9KB but grid-capped at 2/CU,
// Occupancy 23%) is actually reachable. Chunks 13->7 (staging+barriers ~halve).
// LOCKED SEMANTICS (r12/r13/r16 passed, absmax 0.0 — do not change):
//   * per-output sequential-K fmaf chain, k ascending (no K-split, no MFMA)
//   * LIF: m = ((0.8f*m) + cur) - rst with separate __f*_rn roundings
//   * x f32 / weights probed bf16-or-f32 / biases zero-safe probed
//   * output f32: spk_hist (T,B,NO) then m3 (B,NO)
//   * xs staging keeps the tt<tc guard (r15 crash: OOB x read)

typedef unsigned short u16;
typedef unsigned int   u32;

#define TC    16
#define KB    16
#define MAXNH 256
#define MAXNO 4
#define SPAD  260   // spk row pitch f32: %4==0 (b128 align), %32==4

__device__ __forceinline__ float bf2f(u16 u){ union{u32 i;float f;}c; c.i=((u32)u)<<16; return c.f; }
__device__ __forceinline__ float ldin(const void*p,size_t e,int bf){
    return bf ? bf2f(((const u16*)p)[e]) : ((const float*)p)[e];
}
__device__ __forceinline__ float4 ldin4(const void*p,size_t e,int bf){
    if(bf){ const ushort4 u=*reinterpret_cast<const ushort4*>((const u16*)p+e);
            return float4{bf2f(u.x),bf2f(u.y),bf2f(u.z),bf2f(u.w)}; }
    return *reinterpret_cast<const float4*>((const float*)p+e);
}

__global__ __launch_bounds__(256,4)
void snn_f32(const void* __restrict__ x,
             const void* __restrict__ W1, const void* __restrict__ b1,
             const void* __restrict__ W2, const void* __restrict__ b2,
             const void* __restrict__ W3, const void* __restrict__ b3,
             float* __restrict__ out,
             int T,int B,int NI,int NH,int NO)
{
    __shared__ __align__(16) float xs[TC][KB];        // 1 KB
    __shared__ __align__(16) float wt[KB][MAXNH+1];   // 16.45 KB
    __shared__ __align__(16) float spk[TC][SPAD];     // 16.64 KB (s1 then s2)
    __shared__ __align__(16) float w3s[MAXNO][SPAD];  // 4.16 KB (probe red reuses)
    __shared__ float d3[TC][MAXNO];                   // 256 B
    __shared__ int   flg[8];

    const int tid=threadIdx.x, gr=blockIdx.x;         // RB=1: block owns row gr
    int* red=(int*)&w3s[0][0];                        // probe scratch (pre-w3s)

    // ---- per-tensor dtype probes (identical logic to r12..r16) ----
    {
        const u16* ptab[7]={(const u16*)x,(const u16*)W1,(const u16*)W2,
                            (const u16*)W3,(const u16*)b1,(const u16*)b2,(const u16*)b3};
        int ntab[7];
        ntab[0]=1024; ntab[1]=1024; ntab[2]=1024;
        ntab[3]=(NO*NH>=512)?512:NO*NH;
        ntab[4]=(NH<256)?NH:256; ntab[5]=ntab[4];
        ntab[6]=(NO<MAXNO)?NO:MAXNO;
        for(int ti=0;ti<7;++ti){
            const u16* p=ptab[ti]; const int n=ntab[ti];
            int cnt=0,nz=0;
            for(int i=tid;i<n;i+=256){ u16 v=p[i]; if(v)++nz;
                float a=fabsf(bf2f(v)); if(a>1e-3f&&a<64.f)++cnt; }
            red[tid]=cnt; __syncthreads();
            for(int s=128;s>0;s>>=1){ if(tid<s) red[tid]+=red[tid+s]; __syncthreads(); }
            int ca=red[0]; __syncthreads();
            red[tid]=nz; __syncthreads();
            for(int s=128;s>0;s>>=1){ if(tid<s) red[tid]+=red[tid+s]; __syncthreads(); }
            if(tid==0){ int na=red[0]; flg[ti]=(na==0)?-1:((ca*5>n*4)?1:0); }
            __syncthreads();
        }
    }
    const int fx =__builtin_amdgcn_readfirstlane(flg[0]==1);
    const int fw1=__builtin_amdgcn_readfirstlane(flg[1]==1);
    const int fw2=__builtin_amdgcn_readfirstlane(flg[2]==1);
    const int fw3=__builtin_amdgcn_readfirstlane(flg[3]==1);

    float bb1=0.f, bb2=0.f;
    if(tid<NH){ if(flg[4]>=0) bb1=ldin(b1,(size_t)tid,flg[4]==1);
                if(flg[5]>=0) bb2=ldin(b2,(size_t)tid,flg[5]==1); }
    float bb3v=0.f;
    if(tid<NO && flg[6]>=0) bb3v=ldin(b3,(size_t)tid,flg[6]==1);
    __syncthreads();   // probes done before w3s overwrites red

    // stage W3 once; zero spike buffer
    for(int e=tid;e<MAXNO*MAXNH;e+=256){
        int o=e>>8,k=e&255;
        w3s[o][k]=(o<NO&&k<NH)? ldin(W3,(size_t)o*NH+k,fw3):0.f;
    }
    for(int e=tid;e<TC*SPAD;e+=256) (&spk[0][0])[e]=0.f;
    __syncthreads();

    float m1=0.f, m2=0.f, m3r=0.f;
    float acc[TC];

    for(int t0=0;t0<T;t0+=TC){
        const int tc=(T-t0<TC)?(T-t0):TC;

        // ================= layer 1: cur1 = x @ W1^T (sequential k) =========
#pragma unroll
        for(int tt=0;tt<TC;++tt) acc[tt]=0.f;

        for(int kb=0;kb<NI;kb+=KB){
            // stage xs: TC*(KB/4) = 64 quads (threads 0..63); tt<tc guard!
            if(tid<TC*(KB/4)){
                int tt=tid>>2, kq=(tid&3)*4;
                float4 v={0.f,0.f,0.f,0.f};
                if(tt<tc && kb+kq+3<NI)
                    v=ldin4(x,((size_t)(t0+tt)*B+gr)*NI+kb+kq,fx);
                else if(tt<tc){
                    float tmp[4];
#pragma unroll
                    for(int j=0;j<4;++j)
                        tmp[j]=(kb+kq+j<NI)?ldin(x,((size_t)(t0+tt)*B+gr)*NI+kb+kq+j,fx):0.f;
                    v=float4{tmp[0],tmp[1],tmp[2],tmp[3]};
                }
                *reinterpret_cast<float4*>(&xs[tt][kq])=v;
            }
            // stage wt K-transposed: KB*64 = 1024 quads, 4 per thread
            for(int e=tid;e<KB*64;e+=256){
                int kq=(e&3)*4, n=e>>2;
                float4 v={0.f,0.f,0.f,0.f};
                if(n<NH && kb+kq+3<NI) v=ldin4(W1,(size_t)n*NI+kb+kq,fw1);
                else if(n<NH){
                    float tmp[4];
#pragma unroll
                    for(int j=0;j<4;++j)
                        tmp[j]=(kb+kq+j<NI)?ldin(W1,(size_t)n*NI+kb+kq+j,fw1):0.f;
                    v=float4{tmp[0],tmp[1],tmp[2],tmp[3]};
                }
                wt[kq+0][n]=v.x; wt[kq+1][n]=v.y; wt[kq+2][n]=v.z; wt[kq+3][n]=v.w;
            }
            __syncthreads();
            if(tid<NH){
#pragma unroll
                for(int q=0;q<KB/4;++q){
                    const float w0=wt[q*4+0][tid], w1=wt[q*4+1][tid];
                    const float w2=wt[q*4+2][tid], w3v=wt[q*4+3][tid];
#pragma unroll
                    for(int tt=0;tt<TC;++tt){
                        const float4 xv=*reinterpret_cast<const float4*>(&xs[tt][q*4]);
                        float a=acc[tt];
                        a=fmaf(w0,xv.x,a); a=fmaf(w1,xv.y,a);
                        a=fmaf(w2,xv.z,a); a=fmaf(w3v,xv.w,a);
                        acc[tt]=a;
                    }
                }
            }
            __syncthreads();
        }
        // scan 1 -> spk = s1 (reset from PREVIOUS membrane; spike from NEW)
        if(tid<NH){
#pragma unroll
            for(int tt=0;tt<TC;++tt){
                if(tt<tc){
                    float cur=__fadd_rn(acc[tt],bb1);
                    float rst=(m1>1.0f)?1.0f:0.0f;
                    m1=__fsub_rn(__fadd_rn(__fmul_rn(0.8f,m1),cur),rst);
                    spk[tt][tid]=(m1>1.0f)?1.0f:0.0f;
                }
            }
        }
        __syncthreads();

        // ================= layer 2: cur2 = s1 @ W2^T =======================
#pragma unroll
        for(int tt=0;tt<TC;++tt) acc[tt]=0.f;

        for(int kb=0;kb<NH;kb+=KB){
            for(int e=tid;e<KB*64;e+=256){
                int kq=(e&3)*4, n=e>>2;
                float4 v={0.f,0.f,0.f,0.f};
                if(n<NH && kb+kq+3<NH) v=ldin4(W2,(size_t)n*NH+kb+kq,fw2);
                else if(n<NH){
                    float tmp[4];
#pragma unroll
                    for(int j=0;j<4;++j)
                        tmp[j]=(kb+kq+j<NH)?ldin(W2,(size_t)n*NH+kb+kq+j,fw2):0.f;
                    v=float4{tmp[0],tmp[1],tmp[2],tmp[3]};
                }
                wt[kq+0][n]=v.x; wt[kq+1][n]=v.y; wt[kq+2][n]=v.z; wt[kq+3][n]=v.w;
            }
            __syncthreads();
            if(tid<NH){
#pragma unroll
                for(int q=0;q<KB/4;++q){
                    const float w0=wt[q*4+0][tid], w1=wt[q*4+1][tid];
                    const float w2=wt[q*4+2][tid], w3v=wt[q*4+3][tid];
#pragma unroll
                    for(int tt=0;tt<TC;++tt){
                        // fmaf(w, s, a) with s in {0,1} == conditional add (bit-exact)
                        const float4 sv=*reinterpret_cast<const float4*>(&spk[tt][kb+q*4]);
                        float a=acc[tt];
                        a=fmaf(w0,sv.x,a); a=fmaf(w1,sv.y,a);
                        a=fmaf(w2,sv.z,a); a=fmaf(w3v,sv.w,a);
                        acc[tt]=a;
                    }
                }
            }
            __syncthreads();
        }
        // scan 2 -> overwrite spk in place with s2 (s1 dead after L2)
        if(tid<NH){
#pragma unroll
            for(int tt=0;tt<TC;++tt){
                if(tt<tc){
                    float cur=__fadd_rn(acc[tt],bb2);
                    float rst=(m2>1.0f)?1.0f:0.0f;
                    m2=__fsub_rn(__fadd_rn(__fmul_rn(0.8f,m2),cur),rst);
                    spk[tt][tid]=(m2>1.0f)?1.0f:0.0f;
                }
            }
        }
        __syncthreads();

        // ================= layer 3: parallel dots, then sequential scan ====
        if(tid<TC*NO){
            const int tt=tid/NO, o=tid%NO;
            if(tt<tc){
                float a3=0.f;
                int k=0;
                for(; k+3<NH; k+=4){
                    const float4 sv=*reinterpret_cast<const float4*>(&spk[tt][k]);
                    const float4 wv=*reinterpret_cast<const float4*>(&w3s[o][k]);
                    a3=fmaf(wv.x,sv.x,a3); a3=fmaf(wv.y,sv.y,a3);
                    a3=fmaf(wv.z,sv.z,a3); a3=fmaf(wv.w,sv.w,a3);
                }
                for(; k<NH; ++k) a3=fmaf(w3s[o][k],spk[tt][k],a3);
                d3[tt][o]=a3;
            }
        }
        __syncthreads();
        if(tid<NO){
            const int o=tid;
            for(int tt=0;tt<tc;++tt){
                float cur=__fadd_rn(d3[tt][o],bb3v);
                float rst=(m3r>1.0f)?1.0f:0.0f;
                m3r=__fsub_rn(__fadd_rn(__fmul_rn(0.8f,m3r),cur),rst);
                out[((size_t)(t0+tt)*B+gr)*(size_t)NO+o]=(m3r>1.0f)?1.0f:0.0f;
            }
        }
        __syncthreads();
    }

    // final membrane m3 (f32; harness bf16-rounds on compare)
    if(tid<NO)
        out[(size_t)T*B*NO+(size_t)gr*NO+tid]=m3r;
}

// ---------------------------------------------------------------------------
extern "C" void kernel_launch(void* const* d_in, const int* in_sizes, int n_in,
                              void* d_out, int out_size, void* d_ws, size_t ws_size,
                              hipStream_t stream)
{
    const void* x  = d_in[0];
    const void* W1 = d_in[1];
    const void* b1 = d_in[2];
    const void* W2 = d_in[3];
    const void* b2 = d_in[4];
    const void* W3 = d_in[5];
    const void* b3 = d_in[6];

    int NH = in_sizes[2];              if (NH <= 0 || NH > MAXNH) NH = 256;
    int NI = in_sizes[1] / NH;         if (NI <= 0) NI = 512;
    int NO = in_sizes[6];              if (NO <= 0 || NO > MAXNO) NO = 3;
    long TB = (long)in_sizes[0] / NI;
    long BN = (long)out_size / NO;     // T*B + B
    int B = (int)(BN - TB);            if (B <= 0) B = 1024;
    int T = (int)(TB / B);             if (T <= 0) T = 1;

    snn_f32<<<dim3(B), dim3(256), 0, stream>>>(
        x, W1, b1, W2, b2, W3, b3, (float*)d_out, T, B, NI, NH, NO);
}

// Round 18
// 1363.042 us; speedup vs baseline: 1.3159x; 1.3159x over previous
//
#include <hip/hip_runtime.h>

// DynamicDeepSNN r18 — LDS-pressure rebalance: 128-thread blocks, j=2.
// LOCKED SEMANTICS (r12/r13/r16/r17 passed, absmax 0.0 — do not change):
//   * per-output sequential-K fmaf chain, k ascending (no K-split, no MFMA)
//   * LIF: m = ((0.8f*m) + cur) - rst with separate __f*_rn roundings
//   * inputs probed bf16-or-f32 / biases zero-safe probed
//   * output f32: spk_hist (T,B,NO) then m3 (B,NO)
//   * xs staging keeps the tt<tc guard (r15 crash: OOB x read)
// r17 POST-MORTEM: 4/8/16 waves-CU -> 2.45/1.74/1.79 ms: LDS pipe saturates
// at 8 waves; xs b128 broadcasts (16/quad/wave for 64 FMA) dominate.
// r18: 2 waves/block, each thread owns TWO neurons (n=tid, tid+128):
// per quad per wave = 16 broadcasts + 8 b32 for 128 FMA -> LDS/FMA halved;
// per-CU LDS (~512 cyc) == VALU (~512 cyc). 4 blocks/CU via 38.9 KB LDS.

typedef unsigned short u16;
typedef unsigned int   u32;

#define THR   128
#define TC    16
#define KB    16
#define MAXNH 256
#define MAXNO 4
#define SPAD  260   // spk row pitch f32: %4==0 (b128 align), %32==4

__device__ __forceinline__ float bf2f(u16 u){ union{u32 i;float f;}c; c.i=((u32)u)<<16; return c.f; }
__device__ __forceinline__ float ldin(const void*p,size_t e,int bf){
    return bf ? bf2f(((const u16*)p)[e]) : ((const float*)p)[e];
}
__device__ __forceinline__ float4 ldin4(const void*p,size_t e,int bf){
    if(bf){ const ushort4 u=*reinterpret_cast<const ushort4*>((const u16*)p+e);
            return float4{bf2f(u.x),bf2f(u.y),bf2f(u.z),bf2f(u.w)}; }
    return *reinterpret_cast<const float4*>((const float*)p+e);
}

__global__ __launch_bounds__(THR,2)
void snn_f32(const void* __restrict__ x,
             const void* __restrict__ W1, const void* __restrict__ b1,
             const void* __restrict__ W2, const void* __restrict__ b2,
             const void* __restrict__ W3, const void* __restrict__ b3,
             float* __restrict__ out,
             int T,int B,int NI,int NH,int NO)
{
    __shared__ __align__(16) float xs[TC][KB];        // 1 KB
    __shared__ __align__(16) float wt[KB][MAXNH+1];   // 16.45 KB
    __shared__ __align__(16) float spk[TC][SPAD];     // 16.64 KB (s1 then s2)
    __shared__ __align__(16) float w3s[MAXNO][SPAD];  // 4.16 KB (probe red reuses)
    __shared__ float d3[TC][MAXNO];                   // 256 B
    __shared__ int   flg[8];

    const int tid=threadIdx.x, gr=blockIdx.x;         // block owns batch row gr
    int* red=(int*)&w3s[0][0];                        // probe scratch (pre-w3s)

    // ---- per-tensor dtype probes (logic identical to r12..r17) ----
    {
        const u16* ptab[7]={(const u16*)x,(const u16*)W1,(const u16*)W2,
                            (const u16*)W3,(const u16*)b1,(const u16*)b2,(const u16*)b3};
        int ntab[7];
        ntab[0]=1024; ntab[1]=1024; ntab[2]=1024;
        ntab[3]=(NO*NH>=512)?512:NO*NH;
        ntab[4]=(NH<256)?NH:256; ntab[5]=ntab[4];
        ntab[6]=(NO<MAXNO)?NO:MAXNO;
        for(int ti=0;ti<7;++ti){
            const u16* p=ptab[ti]; const int n=ntab[ti];
            int cnt=0,nz=0;
            for(int i=tid;i<n;i+=THR){ u16 v=p[i]; if(v)++nz;
                float a=fabsf(bf2f(v)); if(a>1e-3f&&a<64.f)++cnt; }
            red[tid]=cnt; __syncthreads();
            for(int s=THR/2;s>0;s>>=1){ if(tid<s) red[tid]+=red[tid+s]; __syncthreads(); }
            int ca=red[0]; __syncthreads();
            red[tid]=nz; __syncthreads();
            for(int s=THR/2;s>0;s>>=1){ if(tid<s) red[tid]+=red[tid+s]; __syncthreads(); }
            if(tid==0){ int na=red[0]; flg[ti]=(na==0)?-1:((ca*5>n*4)?1:0); }
            __syncthreads();
        }
    }
    const int fx =__builtin_amdgcn_readfirstlane(flg[0]==1);
    const int fw1=__builtin_amdgcn_readfirstlane(flg[1]==1);
    const int fw2=__builtin_amdgcn_readfirstlane(flg[2]==1);
    const int fw3=__builtin_amdgcn_readfirstlane(flg[3]==1);

    // biases for this thread's two neurons (n = tid, tid+THR)
    float bb1[2]={0.f,0.f}, bb2[2]={0.f,0.f};
#pragma unroll
    for(int jj=0;jj<2;++jj){
        const int n=tid+THR*jj;
        if(n<NH){ if(flg[4]>=0) bb1[jj]=ldin(b1,(size_t)n,flg[4]==1);
                  if(flg[5]>=0) bb2[jj]=ldin(b2,(size_t)n,flg[5]==1); }
    }
    float bb3v=0.f;
    if(tid<NO && flg[6]>=0) bb3v=ldin(b3,(size_t)tid,flg[6]==1);
    __syncthreads();   // probes done before w3s overwrites red

    // stage W3 once; zero spike buffer (pad cols stay 0 forever)
    for(int e=tid;e<MAXNO*MAXNH;e+=THR){
        int o=e>>8,k=e&255;
        w3s[o][k]=(o<NO&&k<NH)? ldin(W3,(size_t)o*NH+k,fw3):0.f;
    }
    for(int e=tid;e<TC*SPAD;e+=THR) (&spk[0][0])[e]=0.f;
    __syncthreads();

    float m1[2]={0.f,0.f}, m2[2]={0.f,0.f}, m3r=0.f;
    float acc[TC][2];

    for(int t0=0;t0<T;t0+=TC){
        const int tc=(T-t0<TC)?(T-t0):TC;

        // ================= layer 1: cur1 = x @ W1^T (sequential k) =========
#pragma unroll
        for(int tt=0;tt<TC;++tt){ acc[tt][0]=0.f; acc[tt][1]=0.f; }

        for(int kb=0;kb<NI;kb+=KB){
            // stage xs: TC*(KB/4)=64 quads (threads 0..63); tt<tc guard!
            if(tid<TC*(KB/4)){
                int tt=tid>>2, kq=(tid&3)*4;
                float4 v={0.f,0.f,0.f,0.f};
                if(tt<tc && kb+kq+3<NI)
                    v=ldin4(x,((size_t)(t0+tt)*B+gr)*NI+kb+kq,fx);
                else if(tt<tc){
                    float tmp[4];
#pragma unroll
                    for(int j=0;j<4;++j)
                        tmp[j]=(kb+kq+j<NI)?ldin(x,((size_t)(t0+tt)*B+gr)*NI+kb+kq+j,fx):0.f;
                    v=float4{tmp[0],tmp[1],tmp[2],tmp[3]};
                }
                *reinterpret_cast<float4*>(&xs[tt][kq])=v;
            }
            // stage wt K-transposed: KB*64=1024 quads, 8 per thread
            for(int e=tid;e<KB*64;e+=THR){
                int kq=(e&3)*4, n=e>>2;
                float4 v={0.f,0.f,0.f,0.f};
                if(n<NH && kb+kq+3<NI) v=ldin4(W1,(size_t)n*NI+kb+kq,fw1);
                else if(n<NH){
                    float tmp[4];
#pragma unroll
                    for(int j=0;j<4;++j)
                        tmp[j]=(kb+kq+j<NI)?ldin(W1,(size_t)n*NI+kb+kq+j,fw1):0.f;
                    v=float4{tmp[0],tmp[1],tmp[2],tmp[3]};
                }
                wt[kq+0][n]=v.x; wt[kq+1][n]=v.y; wt[kq+2][n]=v.z; wt[kq+3][n]=v.w;
            }
            __syncthreads();
#pragma unroll
            for(int q=0;q<KB/4;++q){
                const float wa0=wt[q*4+0][tid],     wa1=wt[q*4+1][tid];
                const float wa2=wt[q*4+2][tid],     wa3=wt[q*4+3][tid];
                const float wb0=wt[q*4+0][tid+THR], wb1=wt[q*4+1][tid+THR];
                const float wb2=wt[q*4+2][tid+THR], wb3=wt[q*4+3][tid+THR];
#pragma unroll
                for(int tt=0;tt<TC;++tt){
                    const float4 xv=*reinterpret_cast<const float4*>(&xs[tt][q*4]);
                    float a=acc[tt][0];
                    a=fmaf(wa0,xv.x,a); a=fmaf(wa1,xv.y,a);
                    a=fmaf(wa2,xv.z,a); a=fmaf(wa3,xv.w,a);
                    acc[tt][0]=a;
                    float b=acc[tt][1];
                    b=fmaf(wb0,xv.x,b); b=fmaf(wb1,xv.y,b);
                    b=fmaf(wb2,xv.z,b); b=fmaf(wb3,xv.w,b);
                    acc[tt][1]=b;
                }
            }
            __syncthreads();
        }
        // scan 1 -> spk = s1 (reset from PREVIOUS membrane; spike from NEW)
#pragma unroll
        for(int jj=0;jj<2;++jj){
            const int n=tid+THR*jj;
            if(n<NH){
#pragma unroll
                for(int tt=0;tt<TC;++tt){
                    if(tt<tc){
                        float cur=__fadd_rn(acc[tt][jj],bb1[jj]);
                        float rst=(m1[jj]>1.0f)?1.0f:0.0f;
                        m1[jj]=__fsub_rn(__fadd_rn(__fmul_rn(0.8f,m1[jj]),cur),rst);
                        spk[tt][n]=(m1[jj]>1.0f)?1.0f:0.0f;
                    }
                }
            }
        }
        __syncthreads();

        // ================= layer 2: cur2 = s1 @ W2^T =======================
#pragma unroll
        for(int tt=0;tt<TC;++tt){ acc[tt][0]=0.f; acc[tt][1]=0.f; }

        for(int kb=0;kb<NH;kb+=KB){
            for(int e=tid;e<KB*64;e+=THR){
                int kq=(e&3)*4, n=e>>2;
                float4 v={0.f,0.f,0.f,0.f};
                if(n<NH && kb+kq+3<NH) v=ldin4(W2,(size_t)n*NH+kb+kq,fw2);
                else if(n<NH){
                    float tmp[4];
#pragma unroll
                    for(int j=0;j<4;++j)
                        tmp[j]=(kb+kq+j<NH)?ldin(W2,(size_t)n*NH+kb+kq+j,fw2):0.f;
                    v=float4{tmp[0],tmp[1],tmp[2],tmp[3]};
                }
                wt[kq+0][n]=v.x; wt[kq+1][n]=v.y; wt[kq+2][n]=v.z; wt[kq+3][n]=v.w;
            }
            __syncthreads();
#pragma unroll
            for(int q=0;q<KB/4;++q){
                const float wa0=wt[q*4+0][tid],     wa1=wt[q*4+1][tid];
                const float wa2=wt[q*4+2][tid],     wa3=wt[q*4+3][tid];
                const float wb0=wt[q*4+0][tid+THR], wb1=wt[q*4+1][tid+THR];
                const float wb2=wt[q*4+2][tid+THR], wb3=wt[q*4+3][tid+THR];
#pragma unroll
                for(int tt=0;tt<TC;++tt){
                    // fmaf(w, s, a) with s in {0,1} == conditional add (bit-exact)
                    const float4 sv=*reinterpret_cast<const float4*>(&spk[tt][kb+q*4]);
                    float a=acc[tt][0];
                    a=fmaf(wa0,sv.x,a); a=fmaf(wa1,sv.y,a);
                    a=fmaf(wa2,sv.z,a); a=fmaf(wa3,sv.w,a);
                    acc[tt][0]=a;
                    float b=acc[tt][1];
                    b=fmaf(wb0,sv.x,b); b=fmaf(wb1,sv.y,b);
                    b=fmaf(wb2,sv.z,b); b=fmaf(wb3,sv.w,b);
                    acc[tt][1]=b;
                }
            }
            __syncthreads();
        }
        // scan 2 -> overwrite spk in place with s2 (s1 dead after L2)
#pragma unroll
        for(int jj=0;jj<2;++jj){
            const int n=tid+THR*jj;
            if(n<NH){
#pragma unroll
                for(int tt=0;tt<TC;++tt){
                    if(tt<tc){
                        float cur=__fadd_rn(acc[tt][jj],bb2[jj]);
                        float rst=(m2[jj]>1.0f)?1.0f:0.0f;
                        m2[jj]=__fsub_rn(__fadd_rn(__fmul_rn(0.8f,m2[jj]),cur),rst);
                        spk[tt][n]=(m2[jj]>1.0f)?1.0f:0.0f;
                    }
                }
            }
        }
        __syncthreads();

        // ================= layer 3: parallel dots, then sequential scan ====
        if(tid<TC*NO){
            const int tt=tid/NO, o=tid%NO;
            if(tt<tc){
                float a3=0.f;
                int k=0;
                for(; k+3<NH; k+=4){
                    const float4 sv=*reinterpret_cast<const float4*>(&spk[tt][k]);
                    const float4 wv=*reinterpret_cast<const float4*>(&w3s[o][k]);
                    a3=fmaf(wv.x,sv.x,a3); a3=fmaf(wv.y,sv.y,a3);
                    a3=fmaf(wv.z,sv.z,a3); a3=fmaf(wv.w,sv.w,a3);
                }
                for(; k<NH; ++k) a3=fmaf(w3s[o][k],spk[tt][k],a3);
                d3[tt][o]=a3;
            }
        }
        __syncthreads();
        if(tid<NO){
            const int o=tid;
            for(int tt=0;tt<tc;++tt){
                float cur=__fadd_rn(d3[tt][o],bb3v);
                float rst=(m3r>1.0f)?1.0f:0.0f;
                m3r=__fsub_rn(__fadd_rn(__fmul_rn(0.8f,m3r),cur),rst);
                out[((size_t)(t0+tt)*B+gr)*(size_t)NO+o]=(m3r>1.0f)?1.0f:0.0f;
            }
        }
        __syncthreads();
    }

    // final membrane m3 (f32; harness bf16-rounds on compare)
    if(tid<NO)
        out[(size_t)T*B*NO+(size_t)gr*NO+tid]=m3r;
}

// ---------------------------------------------------------------------------
extern "C" void kernel_launch(void* const* d_in, const int* in_sizes, int n_in,
                              void* d_out, int out_size, void* d_ws, size_t ws_size,
                              hipStream_t stream)
{
    const void* x  = d_in[0];
    const void* W1 = d_in[1];
    const void* b1 = d_in[2];
    const void* W2 = d_in[3];
    const void* b2 = d_in[4];
    const void* W3 = d_in[5];
    const void* b3 = d_in[6];

    int NH = in_sizes[2];              if (NH <= 0 || NH > MAXNH) NH = 256;
    int NI = in_sizes[1] / NH;         if (NI <= 0) NI = 512;
    int NO = in_sizes[6];              if (NO <= 0 || NO > MAXNO) NO = 3;
    long TB = (long)in_sizes[0] / NI;
    long BN = (long)out_size / NO;     // T*B + B
    int B = (int)(BN - TB);            if (B <= 0) B = 1024;
    int T = (int)(TB / B);             if (T <= 0) T = 1;

    snn_f32<<<dim3(B), dim3(THR), 0, stream>>>(
        x, W1, b1, W2, b2, W3, b3, (float*)d_out, T, B, NI, NH, NO);
}